// Round 4
// baseline (140.037 us; speedup 1.0000x reference)
//
#include <hip/hip_runtime.h>
#include <hip/hip_cooperative_groups.h>
#include <math.h>

namespace cg = cooperative_groups;

// Problem constants
#define BB 512      // batch (edges)
#define NN 4096     // nodes
#define LL 128      // feature dim
#define IN_DIM 385  // 3*L + ND
#define EPB 4       // edges per block (edge phase)
#define GPB 8       // nodes per block (gru phase)

// ---------------------------------------------------------------------------
// Workspace layout (float offsets)
// ---------------------------------------------------------------------------
#define OFF_MSG   0                          // msg_sum (N*L)
#define OFF_CNT   (OFF_MSG + NN * LL)        // cnt (N)
#define OFF_COUNT (OFF_CNT + NN)             // seen_count (1 int) + pad
#define OFF_LIST  (OFF_COUNT + 4)            // seen list (1024 ints)
#define OFF_W1TS  (OFF_LIST + 1024)          // src_w1^T (IN_DIM x L), [k][j]
#define OFF_W1TT  (OFF_W1TS + IN_DIM * LL)   // tar_w1^T
#define OFF_W2TS  (OFF_W1TT + IN_DIM * LL)   // src_w2^T (L x L)
#define OFF_W2TT  (OFF_W2TS + LL * LL)       // tar_w2^T
#define OFF_WIHT  (OFF_W2TT + LL * LL)       // gru_wih^T (L x 3L), [k][row]
#define OFF_WHHT  (OFF_WIHT + 3 * LL * LL)   // gru_whh^T (L x 3L)

// LDS unions for the two compute phases
struct EdgeS {
    float in2[IN_DIM][EPB];      // staged inputs, float4-readable rows
    float part1[2][EPB][LL];
    float h1[LL][EPB];
    float part2[2][EPB][LL];
    int   node_sh[EPB];
};
struct GruS {
    float ah[LL][2 * GPB + 1];   // [k][slot] 0..7=agg, 8..15=h (pad 17)
    float gates[6][GPB][LL];
    int   nodes[GPB];
};

// ---------------------------------------------------------------------------
// One cooperative kernel, three grid-wide phases.
// grid = 256 blocks x 256 threads (1 block/CU, co-resident by construction).
// ---------------------------------------------------------------------------
__global__ __launch_bounds__(256) void fused_kernel(
    const float* __restrict__ x,        // (B, N, 1)
    const float* __restrict__ memory,   // (N, L)
    const float* __restrict__ delta_t,  // (B, N, L)
    const float* __restrict__ sw1, const float* __restrict__ sb1,
    const float* __restrict__ sw2, const float* __restrict__ sb2,
    const float* __restrict__ tw1, const float* __restrict__ tb1,
    const float* __restrict__ tw2, const float* __restrict__ tb2,
    const float* __restrict__ wih, const float* __restrict__ whh,
    const float* __restrict__ bih, const float* __restrict__ bhh,
    const int* __restrict__ source, const int* __restrict__ target,
    float* __restrict__ ws, float* __restrict__ out)
{
    cg::grid_group grid = cg::this_grid();

    const int tid = threadIdx.x;
    const int bid = blockIdx.x;
    const int gi0 = bid * 256 + tid;
    const int gstride = gridDim.x * 256;

    __shared__ __align__(16) char smem_raw[sizeof(GruS)];
    EdgeS& E = *reinterpret_cast<EdgeS*>(smem_raw);
    GruS&  G = *reinterpret_cast<GruS*>(smem_raw);

    // ======== Phase 1: zero accumulators + transpose w1/w2 (edge prereqs) ====
    {
        float4* msg4 = (float4*)(ws + OFF_MSG);
        const float4 z4 = make_float4(0.f, 0.f, 0.f, 0.f);
        for (int idx = gi0; idx < NN * LL / 4; idx += gstride) msg4[idx] = z4;
        for (int idx = gi0; idx < NN; idx += gstride) ws[OFF_CNT + idx] = 0.0f;
        if (gi0 == 0) ((int*)ws)[OFF_COUNT] = 0;

        for (int idx = gi0; idx < IN_DIM * LL; idx += gstride) {
            const int k = idx >> 7, j = idx & 127;
            ws[OFF_W1TS + idx] = sw1[j * IN_DIM + k];
            ws[OFF_W1TT + idx] = tw1[j * IN_DIM + k];
        }
        for (int idx = gi0; idx < LL * LL; idx += gstride) {
            const int k = idx >> 7, j = idx & 127;
            ws[OFF_W2TS + idx] = sw2[j * LL + k];
            ws[OFF_W2TT + idx] = tw2[j * LL + k];
        }
    }
    grid.sync();

    // ======== Phase 2: edge messages + (copy, gru transposes) ================
    {
        const int side  = bid & 1;
        const int chunk = bid >> 1;          // 0 .. BB/EPB-1
        const int g     = tid >> 7;          // k-split group
        const int j     = tid & 127;         // output feature

        const float* w1T = ws + (side ? OFF_W1TT : OFF_W1TS);
        const float* w2T = ws + (side ? OFF_W2TT : OFF_W2TS);
        const float* b1  = side ? tb1 : sb1;
        const float* b2  = side ? tb2 : sb2;

        // Stage EPB edges' input vectors.
        #pragma unroll
        for (int e = 0; e < EPB; ++e) {
            const int eg = chunk * EPB + e;
            const int s = source[eg], t = target[eg];
            const int node  = side ? t : s;
            const int other = side ? s : t;
            if (tid == 0) E.node_sh[e] = node;
            for (int idx = tid; idx < IN_DIM; idx += 256) {
                float v;
                if (idx < LL)           v = memory[node * LL + idx];
                else if (idx < 2 * LL)  v = memory[other * LL + (idx - LL)];
                else if (idx < 3 * LL)  v = delta_t[((size_t)eg * NN + node) * LL + (idx - 2 * LL)];
                else                    v = x[(size_t)eg * NN + node];
                E.in2[idx][e] = v;
            }
        }
        __syncthreads();

        // Layer 1 (k-split: g0 -> [0,193), g1 -> [193,385))
        {
            const int k0 = g ? 193 : 0;
            const int k1 = g ? IN_DIM : 193;
            float a[EPB] = {0.f, 0.f, 0.f, 0.f};
            #pragma unroll 4
            for (int k = k0; k < k1; ++k) {
                const float w = w1T[k * LL + j];
                const float4 iv = *(const float4*)&E.in2[k][0];
                a[0] = fmaf(w, iv.x, a[0]);
                a[1] = fmaf(w, iv.y, a[1]);
                a[2] = fmaf(w, iv.z, a[2]);
                a[3] = fmaf(w, iv.w, a[3]);
            }
            #pragma unroll
            for (int e = 0; e < EPB; ++e) E.part1[g][e][j] = a[e];
        }
        __syncthreads();

        #pragma unroll
        for (int q = 0; q < EPB / 2; ++q) {
            const int e = g * (EPB / 2) + q;
            E.h1[j][e] = fmaxf(E.part1[0][e][j] + E.part1[1][e][j] + b1[j], 0.0f);
        }
        __syncthreads();

        // Layer 2 (k-split halves of 128)
        {
            const int k0 = g * 64, k1 = k0 + 64;
            float a[EPB] = {0.f, 0.f, 0.f, 0.f};
            #pragma unroll 4
            for (int k = k0; k < k1; ++k) {
                const float w = w2T[k * LL + j];
                const float4 hv = *(const float4*)&E.h1[k][0];
                a[0] = fmaf(w, hv.x, a[0]);
                a[1] = fmaf(w, hv.y, a[1]);
                a[2] = fmaf(w, hv.z, a[2]);
                a[3] = fmaf(w, hv.w, a[3]);
            }
            #pragma unroll
            for (int e = 0; e < EPB; ++e) E.part2[g][e][j] = a[e];
        }
        __syncthreads();

        // Final messages; atomic segment-sum.
        #pragma unroll
        for (int q = 0; q < EPB / 2; ++q) {
            const int e = g * (EPB / 2) + q;
            const float m = E.part2[0][e][j] + E.part2[1][e][j] + b2[j];
            atomicAdd(ws + OFF_MSG + E.node_sh[e] * LL + j, m);
        }
        if (tid < EPB) {
            const int node = E.node_sh[tid];
            const float old = atomicAdd(ws + OFF_CNT + node, 1.0f);
            if (old == 0.0f) {
                const int pos = atomicAdd((int*)ws + OFF_COUNT, 1);
                ((int*)ws)[OFF_LIST + pos] = node;
            }
        }

        // Work needed only by phase 3: passthrough copy + GRU transposes.
        {
            float4* out4 = (float4*)out;
            const float4* mem4 = (const float4*)memory;
            for (int idx = gi0; idx < NN * LL / 4; idx += gstride)
                out4[idx] = mem4[idx];
            for (int idx = gi0; idx < 3 * LL * LL; idx += gstride) {
                const int k = idx / 384, r = idx - k * 384;
                ws[OFF_WIHT + idx] = wih[r * LL + k];
                ws[OFF_WHHT + idx] = whh[r * LL + k];
            }
        }
    }
    grid.sync();

    // ======== Phase 3: GRU over the compact seen list ========================
    {
        const int g = tid >> 7, j = tid & 127;
        const int scount = ((const int*)ws)[OFF_COUNT];
        const int base = bid * GPB;
        if (base >= scount) return;
        const int nact = min(GPB, scount - base);

        if (tid < GPB)
            G.nodes[tid] = (base + tid < scount)
                           ? ((const int*)ws)[OFF_LIST + base + tid] : -1;
        __syncthreads();

        #pragma unroll
        for (int gi = 0; gi < GPB; ++gi) {
            const int node = G.nodes[gi];
            if (g == 0) {
                float v = 0.0f;
                if (node >= 0) {
                    const float c = ws[OFF_CNT + node];
                    v = ws[OFF_MSG + node * LL + j] / c;
                }
                G.ah[j][gi] = v;
            } else {
                G.ah[j][GPB + gi] = (node >= 0) ? memory[node * LL + j] : 0.0f;
            }
        }
        __syncthreads();

        const float* wT = ws + (g ? OFF_WHHT : OFF_WIHT);
        float a0[GPB] = {}, a1[GPB] = {}, a2[GPB] = {};
        #pragma unroll 2
        for (int k = 0; k < LL; ++k) {
            const float w0 = wT[k * 384 + j];
            const float w1 = wT[k * 384 + 128 + j];
            const float w2 = wT[k * 384 + 256 + j];
            #pragma unroll
            for (int gi = 0; gi < GPB; ++gi) {
                const float v = G.ah[k][g * GPB + gi];   // broadcast
                a0[gi] = fmaf(w0, v, a0[gi]);
                a1[gi] = fmaf(w1, v, a1[gi]);
                a2[gi] = fmaf(w2, v, a2[gi]);
            }
        }
        #pragma unroll
        for (int gi = 0; gi < GPB; ++gi) {
            G.gates[g * 3 + 0][gi][j] = a0[gi];
            G.gates[g * 3 + 1][gi][j] = a1[gi];
            G.gates[g * 3 + 2][gi][j] = a2[gi];
        }
        __syncthreads();

        const int total = nact * LL;
        for (int o = tid; o < total; o += 256) {
            const int gi = o >> 7, jj = o & 127;
            const int node = G.nodes[gi];
            const float ir = G.gates[0][gi][jj] + bih[jj];
            const float iz = G.gates[1][gi][jj] + bih[LL + jj];
            const float inn = G.gates[2][gi][jj] + bih[2 * LL + jj];
            const float hr = G.gates[3][gi][jj] + bhh[jj];
            const float hz = G.gates[4][gi][jj] + bhh[LL + jj];
            const float hn = G.gates[5][gi][jj] + bhh[2 * LL + jj];
            const float r = 1.0f / (1.0f + __expf(-(ir + hr)));
            const float z = 1.0f / (1.0f + __expf(-(iz + hz)));
            const float n = tanhf(inn + r * hn);
            const float h = G.ah[jj][GPB + gi];
            out[node * LL + jj] = (1.0f - z) * n + z * h;
        }
    }
}

// ---------------------------------------------------------------------------
extern "C" void kernel_launch(void* const* d_in, const int* in_sizes, int n_in,
                              void* d_out, int out_size, void* d_ws, size_t ws_size,
                              hipStream_t stream) {
    const float* x        = (const float*)d_in[0];
    const float* memory   = (const float*)d_in[1];
    const float* delta_t  = (const float*)d_in[2];
    const float* src_w1   = (const float*)d_in[3];
    const float* src_b1   = (const float*)d_in[4];
    const float* src_w2   = (const float*)d_in[5];
    const float* src_b2   = (const float*)d_in[6];
    const float* tar_w1   = (const float*)d_in[7];
    const float* tar_b1   = (const float*)d_in[8];
    const float* tar_w2   = (const float*)d_in[9];
    const float* tar_b2   = (const float*)d_in[10];
    const float* gru_wih  = (const float*)d_in[11];
    const float* gru_whh  = (const float*)d_in[12];
    const float* gru_bih  = (const float*)d_in[13];
    const float* gru_bhh  = (const float*)d_in[14];
    const int*   source   = (const int*)d_in[15];
    const int*   target   = (const int*)d_in[16];

    float* out = (float*)d_out;
    float* ws  = (float*)d_ws;

    void* args[] = {
        (void*)&x, (void*)&memory, (void*)&delta_t,
        (void*)&src_w1, (void*)&src_b1, (void*)&src_w2, (void*)&src_b2,
        (void*)&tar_w1, (void*)&tar_b1, (void*)&tar_w2, (void*)&tar_b2,
        (void*)&gru_wih, (void*)&gru_whh, (void*)&gru_bih, (void*)&gru_bhh,
        (void*)&source, (void*)&target,
        (void*)&ws, (void*)&out
    };

    hipLaunchCooperativeKernel((void*)fused_kernel, dim3(256), dim3(256),
                               args, 0, stream);
}

// Round 5
// 36.925 us; speedup vs baseline: 3.7924x; 3.7924x over previous
//
#include <hip/hip_runtime.h>
#include <math.h>

// Problem constants
#define BB 512      // batch (edges)
#define NN 4096     // nodes
#define LL 128      // feature dim
#define IN_DIM 385  // 3*L + ND
#define IN_PAD 388  // padded to multiple of 4
#define NK4_1 97    // IN_PAD/4 k-groups, layer 1
#define NK4_2 32    // LL/4 k-groups, layer 2 / GRU
#define EPB 2       // edges per block (edge kernel)
#define GPB 4       // nodes per block (gru kernel)

// ---------------------------------------------------------------------------
// Workspace layout (float offsets, all float4-aligned where needed)
// ---------------------------------------------------------------------------
#define OFF_MSG   0                           // msg_sum (N*L)
#define OFF_CNT   (OFF_MSG + NN * LL)         // cnt (N)
#define OFF_COUNT (OFF_CNT + NN)              // seen_count (1 int) + pad
#define OFF_LIST  (OFF_COUNT + 4)             // seen list (1024 ints)
#define OFF_W1PS  529416                      // src_w1 packed f4[k4*128+j]
#define OFF_W1PT  (OFF_W1PS + NK4_1 * LL * 4)
#define OFF_W2PS  (OFF_W1PT + NK4_1 * LL * 4)
#define OFF_W2PT  (OFF_W2PS + NK4_2 * LL * 4)
#define OFF_WIHP  (OFF_W2PT + NK4_2 * LL * 4) // f4[(gate*32+k4)*128+j]
#define OFF_WHHP  (OFF_WIHP + 3 * NK4_2 * LL * 4)
// end = 759816 floats ~ 3.04 MB

// ---------------------------------------------------------------------------
// Prep: passthrough copy, zero accumulators, float4 k-packed weight layouts.
// ---------------------------------------------------------------------------
__global__ __launch_bounds__(256) void prep_kernel(
    const float* __restrict__ memory,
    const float* __restrict__ sw1, const float* __restrict__ tw1,
    const float* __restrict__ sw2, const float* __restrict__ tw2,
    const float* __restrict__ wih, const float* __restrict__ whh,
    float* __restrict__ ws, float* __restrict__ out)
{
    const int i = blockIdx.x * 256 + threadIdx.x;
    const int stride = gridDim.x * 256;

    float4* out4 = (float4*)out;
    const float4* mem4 = (const float4*)memory;
    float4* msg4 = (float4*)(ws + OFF_MSG);
    const float4 z4 = make_float4(0.f, 0.f, 0.f, 0.f);
    for (int idx = i; idx < NN * LL / 4; idx += stride) {
        out4[idx] = mem4[idx];
        msg4[idx] = z4;
    }
    for (int idx = i; idx < NN; idx += stride)
        ws[OFF_CNT + idx] = 0.0f;
    if (i == 0)
        ((int*)ws)[OFF_COUNT] = 0;

    // layer-1 weights: (L, IN) -> f4 w1p[k4*L + j] = w1[j][4k4..4k4+3], 0-pad
    float4* w1ps = (float4*)(ws + OFF_W1PS);
    float4* w1pt = (float4*)(ws + OFF_W1PT);
    for (int idx = i; idx < NK4_1 * LL; idx += stride) {
        const int k4 = idx >> 7, j = idx & 127;
        const int k = k4 * 4;
        float4 a, b;
        a.x = sw1[j * IN_DIM + k];     b.x = tw1[j * IN_DIM + k];
        a.y = sw1[j * IN_DIM + k + 1]; b.y = tw1[j * IN_DIM + k + 1];
        a.z = sw1[j * IN_DIM + k + 2]; b.z = tw1[j * IN_DIM + k + 2];
        if (k + 3 < IN_DIM) { a.w = sw1[j * IN_DIM + k + 3]; b.w = tw1[j * IN_DIM + k + 3]; }
        else                { a.w = 0.f; b.w = 0.f; }
        if (k + 2 >= IN_DIM) { a.z = 0.f; b.z = 0.f; }
        if (k + 1 >= IN_DIM) { a.y = 0.f; b.y = 0.f; }
        w1ps[idx] = a; w1pt[idx] = b;
    }
    // layer-2 weights: (L, L) -> f4 w2p[k4*L + j]
    float4* w2ps = (float4*)(ws + OFF_W2PS);
    float4* w2pt = (float4*)(ws + OFF_W2PT);
    for (int idx = i; idx < NK4_2 * LL; idx += stride) {
        const int k4 = idx >> 7, j = idx & 127;
        const int k = k4 * 4;
        w2ps[idx] = make_float4(sw2[j * LL + k], sw2[j * LL + k + 1],
                                sw2[j * LL + k + 2], sw2[j * LL + k + 3]);
        w2pt[idx] = make_float4(tw2[j * LL + k], tw2[j * LL + k + 1],
                                tw2[j * LL + k + 2], tw2[j * LL + k + 3]);
    }
    // GRU weights: (3L, L) -> f4 wp[(gate*32+k4)*L + j] = w[gate*128+j][4k4..]
    float4* wihp = (float4*)(ws + OFF_WIHP);
    float4* whhp = (float4*)(ws + OFF_WHHP);
    for (int idx = i; idx < 3 * NK4_2 * LL; idx += stride) {
        const int j = idx & 127;
        const int gk = idx >> 7;            // gate*32 + k4
        const int gate = gk >> 5, k4 = gk & 31;
        const int row = gate * LL + j, k = k4 * 4;
        wihp[idx] = make_float4(wih[row * LL + k], wih[row * LL + k + 1],
                                wih[row * LL + k + 2], wih[row * LL + k + 3]);
        whhp[idx] = make_float4(whh[row * LL + k], whh[row * LL + k + 1],
                                whh[row * LL + k + 2], whh[row * LL + k + 3]);
    }
}

// ---------------------------------------------------------------------------
// Edge messages: one block = one side of EPB=2 edges; 512 blocks (2/CU).
// ---------------------------------------------------------------------------
__global__ __launch_bounds__(256) void edge_msg_kernel(
    const float* __restrict__ x,        // (B, N, 1)
    const float* __restrict__ memory,   // (N, L)
    const float* __restrict__ delta_t,  // (B, N, L)
    const float* __restrict__ sb1, const float* __restrict__ sb2,
    const float* __restrict__ tb1, const float* __restrict__ tb2,
    const int* __restrict__ source, const int* __restrict__ target,
    float* __restrict__ ws)
{
    const int side  = blockIdx.x & 1;
    const int chunk = blockIdx.x >> 1;
    const int tid   = threadIdx.x;
    const int g     = tid >> 7;
    const int j     = tid & 127;

    __shared__ float in2[IN_PAD][EPB];
    __shared__ float h1[LL][EPB];
    __shared__ float part1[2][EPB][LL];
    __shared__ float part2[2][EPB][LL];
    __shared__ int   node_sh[EPB];

    const float4* w1p = (const float4*)(ws + (side ? OFF_W1PT : OFF_W1PS));
    const float4* w2p = (const float4*)(ws + (side ? OFF_W2PT : OFF_W2PS));
    const float* b1  = side ? tb1 : sb1;
    const float* b2  = side ? tb2 : sb2;

    #pragma unroll
    for (int e = 0; e < EPB; ++e) {
        const int eg = chunk * EPB + e;
        const int s = source[eg], t = target[eg];
        const int node  = side ? t : s;
        const int other = side ? s : t;
        if (tid == 0) node_sh[e] = node;
        for (int idx = tid; idx < IN_PAD; idx += 256) {
            float v = 0.0f;
            if (idx < LL)           v = memory[node * LL + idx];
            else if (idx < 2 * LL)  v = memory[other * LL + (idx - LL)];
            else if (idx < 3 * LL)  v = delta_t[((size_t)eg * NN + node) * LL + (idx - 2 * LL)];
            else if (idx == 3 * LL) v = x[(size_t)eg * NN + node];
            in2[idx][e] = v;
        }
    }
    __syncthreads();

    // Layer 1: g0 -> k4 [0,49), g1 -> [49,97)
    {
        const int k40 = g ? 49 : 0;
        const int k41 = g ? NK4_1 : 49;
        float a0 = 0.f, a1 = 0.f;
        #pragma unroll 4
        for (int k4 = k40; k4 < k41; ++k4) {
            const float4 w  = w1p[k4 * LL + j];
            const float4 i0 = *(const float4*)&in2[k4 * 4][0];
            const float4 i1 = *(const float4*)&in2[k4 * 4 + 2][0];
            a0 = fmaf(w.x, i0.x, a0); a1 = fmaf(w.x, i0.y, a1);
            a0 = fmaf(w.y, i0.z, a0); a1 = fmaf(w.y, i0.w, a1);
            a0 = fmaf(w.z, i1.x, a0); a1 = fmaf(w.z, i1.y, a1);
            a0 = fmaf(w.w, i1.z, a0); a1 = fmaf(w.w, i1.w, a1);
        }
        part1[g][0][j] = a0;
        part1[g][1][j] = a1;
    }
    __syncthreads();

    h1[j][g] = fmaxf(part1[0][g][j] + part1[1][g][j] + b1[j], 0.0f);
    __syncthreads();

    // Layer 2: g0 -> k4 [0,16), g1 -> [16,32)
    {
        const int k40 = g * 16, k41 = k40 + 16;
        float a0 = 0.f, a1 = 0.f;
        #pragma unroll 4
        for (int k4 = k40; k4 < k41; ++k4) {
            const float4 w  = w2p[k4 * LL + j];
            const float4 h0 = *(const float4*)&h1[k4 * 4][0];
            const float4 h2 = *(const float4*)&h1[k4 * 4 + 2][0];
            a0 = fmaf(w.x, h0.x, a0); a1 = fmaf(w.x, h0.y, a1);
            a0 = fmaf(w.y, h0.z, a0); a1 = fmaf(w.y, h0.w, a1);
            a0 = fmaf(w.z, h2.x, a0); a1 = fmaf(w.z, h2.y, a1);
            a0 = fmaf(w.w, h2.z, a0); a1 = fmaf(w.w, h2.w, a1);
        }
        part2[g][0][j] = a0;
        part2[g][1][j] = a1;
    }
    __syncthreads();

    {
        const float m = part2[0][g][j] + part2[1][g][j] + b2[j];
        atomicAdd(ws + OFF_MSG + node_sh[g] * LL + j, m);
    }
    if (tid < EPB) {
        const int node = node_sh[tid];
        const float old = atomicAdd(ws + OFF_CNT + node, 1.0f);
        if (old == 0.0f) {
            const int pos = atomicAdd((int*)ws + OFF_COUNT, 1);
            ((int*)ws)[OFF_LIST + pos] = node;
        }
    }
}

// ---------------------------------------------------------------------------
// GRU over the compact seen list. GPB=4 nodes/block, 256 blocks, gate-split.
// ---------------------------------------------------------------------------
__global__ __launch_bounds__(256) void gru_kernel(
    const float* __restrict__ memory,
    const float* __restrict__ bih, const float* __restrict__ bhh,
    float* __restrict__ ws, float* __restrict__ out)
{
    const int tid = threadIdx.x;
    const int g = tid >> 7, j = tid & 127;
    const int scount = ((const int*)ws)[OFF_COUNT];
    const int base = blockIdx.x * GPB;
    if (base >= scount) return;
    const int nact = min(GPB, scount - base);

    __shared__ float ah[LL][2 * GPB];        // [k][slot] 0..3=agg, 4..7=h
    __shared__ float gates[6][GPB][LL];
    __shared__ int   nodes_sh[GPB];

    if (tid < GPB)
        nodes_sh[tid] = (base + tid < scount)
                        ? ((const int*)ws)[OFF_LIST + base + tid] : -1;
    __syncthreads();

    #pragma unroll
    for (int gi = 0; gi < GPB; ++gi) {
        const int node = nodes_sh[gi];
        if (g == 0) {
            float v = 0.0f;
            if (node >= 0) {
                const float c = ws[OFF_CNT + node];
                v = ws[OFF_MSG + node * LL + j] / c;
            }
            ah[j][gi] = v;
        } else {
            ah[j][GPB + gi] = (node >= 0) ? memory[node * LL + j] : 0.0f;
        }
    }
    __syncthreads();

    const float4* wp = (const float4*)(ws + (g ? OFF_WHHP : OFF_WIHP));
    float a0[GPB] = {}, a1[GPB] = {}, a2[GPB] = {};
    #pragma unroll 2
    for (int k4 = 0; k4 < NK4_2; ++k4) {
        const float4 w0 = wp[(0 * NK4_2 + k4) * LL + j];
        const float4 w1 = wp[(1 * NK4_2 + k4) * LL + j];
        const float4 w2 = wp[(2 * NK4_2 + k4) * LL + j];
        const float w0a[4] = {w0.x, w0.y, w0.z, w0.w};
        const float w1a[4] = {w1.x, w1.y, w1.z, w1.w};
        const float w2a[4] = {w2.x, w2.y, w2.z, w2.w};
        #pragma unroll
        for (int c = 0; c < 4; ++c) {
            const float4 v4 = *(const float4*)&ah[k4 * 4 + c][g * GPB];
            const float va[4] = {v4.x, v4.y, v4.z, v4.w};
            #pragma unroll
            for (int gi = 0; gi < GPB; ++gi) {
                a0[gi] = fmaf(w0a[c], va[gi], a0[gi]);
                a1[gi] = fmaf(w1a[c], va[gi], a1[gi]);
                a2[gi] = fmaf(w2a[c], va[gi], a2[gi]);
            }
        }
    }
    #pragma unroll
    for (int gi = 0; gi < GPB; ++gi) {
        gates[g * 3 + 0][gi][j] = a0[gi];
        gates[g * 3 + 1][gi][j] = a1[gi];
        gates[g * 3 + 2][gi][j] = a2[gi];
    }
    __syncthreads();

    const int total = nact * LL;
    for (int o = tid; o < total; o += 256) {
        const int gi = o >> 7, jj = o & 127;
        const int node = nodes_sh[gi];
        const float ir = gates[0][gi][jj] + bih[jj];
        const float iz = gates[1][gi][jj] + bih[LL + jj];
        const float inn = gates[2][gi][jj] + bih[2 * LL + jj];
        const float hr = gates[3][gi][jj] + bhh[jj];
        const float hz = gates[4][gi][jj] + bhh[LL + jj];
        const float hn = gates[5][gi][jj] + bhh[2 * LL + jj];
        const float r = 1.0f / (1.0f + __expf(-(ir + hr)));
        const float z = 1.0f / (1.0f + __expf(-(iz + hz)));
        const float n = tanhf(inn + r * hn);
        const float h = ah[jj][GPB + gi];
        out[node * LL + jj] = (1.0f - z) * n + z * h;
    }
}

// ---------------------------------------------------------------------------
extern "C" void kernel_launch(void* const* d_in, const int* in_sizes, int n_in,
                              void* d_out, int out_size, void* d_ws, size_t ws_size,
                              hipStream_t stream) {
    const float* x        = (const float*)d_in[0];
    const float* memory   = (const float*)d_in[1];
    const float* delta_t  = (const float*)d_in[2];
    const float* src_w1   = (const float*)d_in[3];
    const float* src_b1   = (const float*)d_in[4];
    const float* src_w2   = (const float*)d_in[5];
    const float* src_b2   = (const float*)d_in[6];
    const float* tar_w1   = (const float*)d_in[7];
    const float* tar_b1   = (const float*)d_in[8];
    const float* tar_w2   = (const float*)d_in[9];
    const float* tar_b2   = (const float*)d_in[10];
    const float* gru_wih  = (const float*)d_in[11];
    const float* gru_whh  = (const float*)d_in[12];
    const float* gru_bih  = (const float*)d_in[13];
    const float* gru_bhh  = (const float*)d_in[14];
    const int*   source   = (const int*)d_in[15];
    const int*   target   = (const int*)d_in[16];

    float* out = (float*)d_out;
    float* ws  = (float*)d_ws;

    prep_kernel<<<512, 256, 0, stream>>>(
        memory, src_w1, tar_w1, src_w2, tar_w2, gru_wih, gru_whh, ws, out);

    edge_msg_kernel<<<2 * (BB / EPB), 256, 0, stream>>>(
        x, memory, delta_t, src_b1, src_b2, tar_b1, tar_b2,
        source, target, ws);

    gru_kernel<<<1024 / GPB, 256, 0, stream>>>(
        memory, gru_bih, gru_bhh, ws, out);
}